// Round 8
// baseline (377.933 us; speedup 1.0000x reference)
//
#include <hip/hip_runtime.h>

typedef unsigned short ushort;
typedef unsigned int uint;
typedef __attribute__((ext_vector_type(8))) short short8;
typedef __attribute__((ext_vector_type(4))) float float4v;

#define D_MODEL 1024
#define NH 16
#define DH 64
#define BATCH 2
#define SEQ 1024
#define MEMLEN 1024
#define TOT 2048

__device__ __forceinline__ float b2f(ushort u) {
  return __uint_as_float(((uint)u) << 16);
}
__device__ __forceinline__ ushort f2b(float f) {
  uint i = __float_as_uint(f);
  uint r = (i + 0x7fffu + ((i >> 16) & 1u)) >> 16;
  return (ushort)r;
}
__device__ __forceinline__ void gld16(const ushort* g, ushort* l) {
  __builtin_amdgcn_global_load_lds(
      (const __attribute__((address_space(1))) void*)g,
      (__attribute__((address_space(3))) void*)l, 16, 0, 0);
}

// ------------------------------------------------- concat + cast to bf16 ----
__global__ __launch_bounds__(256) void concat_cvt_kernel(
    const float* __restrict__ x, const float* __restrict__ mem,
    ushort* __restrict__ xt, ushort* __restrict__ xb) {
  int idx = blockIdx.x * 256 + threadIdx.x;
  int row = idx >> 7;
  int c8 = (idx & 127) << 3;
  int b = row >> 11;
  int i = row & 2047;
  const float* src = (i < MEMLEN) ? &mem[((b << 10) + i) * D_MODEL]
                                  : &x[((b << 10) + (i - MEMLEN)) * D_MODEL];
  float4 f0 = *(const float4*)(&src[c8]);
  float4 f1 = *(const float4*)(&src[c8 + 4]);
  ushort u[8] = {f2b(f0.x), f2b(f0.y), f2b(f0.z), f2b(f0.w),
                 f2b(f1.x), f2b(f1.y), f2b(f1.z), f2b(f1.w)};
  *(uint4*)(&xt[row * D_MODEL + c8]) = *(const uint4*)u;
  if (i >= MEMLEN)
    *(uint4*)(&xb[((b << 10) + (i - MEMLEN)) * D_MODEL + c8]) = *(const uint4*)u;
}

// ---------------- rel -> bf16 and mask -> bf16*-1e9, one launch -------------
__global__ __launch_bounds__(256) void cvt2_kernel(
    const float* __restrict__ rel, const float* __restrict__ mask,
    ushort* __restrict__ relb, ushort* __restrict__ maskb) {
  int idx = blockIdx.x * 256 + threadIdx.x;
  const float* in;
  ushort* out;
  float sc;
  if (idx < 262144) {
    in = rel; out = relb; sc = 1.0f;
  } else {
    idx -= 262144; in = mask; out = maskb; sc = -1e9f;
  }
  int base = idx << 3;
  float4 f0 = *(const float4*)(&in[base]);
  float4 f1 = *(const float4*)(&in[base + 4]);
  ushort u[8] = {f2b(f0.x * sc), f2b(f0.y * sc), f2b(f0.z * sc),
                 f2b(f0.w * sc), f2b(f1.x * sc), f2b(f1.y * sc),
                 f2b(f1.z * sc), f2b(f1.w * sc)};
  *(uint4*)(&out[base]) = *(const uint4*)u;
}

// --------------------------- 5x transpose + cast to bf16 (one launch) -------
__global__ __launch_bounds__(256) void transpose_cvt5_kernel(
    const float* __restrict__ W0, const float* __restrict__ W1,
    const float* __restrict__ W2, const float* __restrict__ W3,
    const float* __restrict__ W4, ushort* __restrict__ T0,
    ushort* __restrict__ T1, ushort* __restrict__ T2, ushort* __restrict__ T3,
    ushort* __restrict__ T4) {
  __shared__ ushort tle[32][33];
  const float* W;
  ushort* T;
  switch (blockIdx.z) {
    case 0: W = W0; T = T0; break;
    case 1: W = W1; T = T1; break;
    case 2: W = W2; T = T2; break;
    case 3: W = W3; T = T3; break;
    default: W = W4; T = T4; break;
  }
  const int bx = blockIdx.x * 32, by = blockIdx.y * 32;
  const int tx = threadIdx.x & 31, ty = threadIdx.x >> 5;
#pragma unroll
  for (int j = 0; j < 32; j += 8)
    tle[ty + j][tx] = f2b(W[(by + ty + j) * 1024 + bx + tx]);
  __syncthreads();
#pragma unroll
  for (int j = 0; j < 32; j += 8)
    T[(bx + ty + j) * 1024 + by + tx] = tle[tx][ty + j];
}

// ------------------------------------- V transpose: kv cols -> vt[b][d][t] --
__global__ __launch_bounds__(256) void vtrans_kernel(
    const ushort* __restrict__ kv, ushort* __restrict__ vt) {
  __shared__ ushort tle[32][76];
  const int gx = blockIdx.x;
  const int gy = blockIdx.y;
  const int tid = threadIdx.x;
  const int r = tid >> 3, c8 = (tid & 7) * 8;
  *(uint4*)(&tle[r][c8]) =
      *(const uint4*)(&kv[(gx * 32 + r) * 2048 + 1024 + gy * 64 + c8]);
  __syncthreads();
  const int dr = tid >> 2, tc8 = (tid & 3) * 8;
  const int bb = (gx * 32) >> 11, tbase = (gx * 32) & 2047;
  ushort tmp[8];
#pragma unroll
  for (int j = 0; j < 8; ++j) tmp[j] = tle[tc8 + j][dr];
  *(uint4*)(&vt[((bb << 10) + gy * 64 + dr) * 2048 + tbase + tc8]) =
      *(const uint4*)tmp;
}

// -------------------------------------------------- 128x128 m97-style GEMM --
// KV projection: cols<1024 = K (scaled 0.125 with bke), cols>=1024 = V (bv).
__global__ __launch_bounds__(256) void gemm128_kernel(
    const ushort* __restrict__ A, const ushort* __restrict__ BT,
    const float* __restrict__ b0, const float* __restrict__ b1,
    ushort* __restrict__ Cout, int M, int N, int K) {
  __shared__ ushort As[128 * 32];
  __shared__ ushort Bs[128 * 32];
  const int m0 = blockIdx.x * 128, n0 = blockIdx.y * 128;
  const int tid = threadIdx.x;
  const int w = tid >> 6, lane = tid & 63, m15 = lane & 15, q4 = lane >> 4;
  const int wm = w & 1, wn = w >> 1;
  float4v acc[4][4] = {};
  const int c0 = tid, c1 = tid + 256;
  const int r0 = c0 >> 2, u0 = (c0 & 3) * 8;
  const int r1 = c1 >> 2, u1 = (c1 & 3) * 8;

  for (int kk = 0; kk < K; kk += 32) {
    __syncthreads();
    gld16(&A[(m0 + r0) * K + kk + u0], &As[c0 * 8]);
    gld16(&A[(m0 + r1) * K + kk + u1], &As[c1 * 8]);
    gld16(&BT[(n0 + r0) * K + kk + u0], &Bs[c0 * 8]);
    gld16(&BT[(n0 + r1) * K + kk + u1], &Bs[c1 * 8]);
    __syncthreads();
    short8 af[4], bf[4];
#pragma unroll
    for (int i = 0; i < 4; ++i)
      af[i] = *(const short8*)(&As[(wm * 64 + i * 16 + m15) * 32 + q4 * 8]);
#pragma unroll
    for (int j = 0; j < 4; ++j)
      bf[j] = *(const short8*)(&Bs[(wn * 64 + j * 16 + m15) * 32 + q4 * 8]);
#pragma unroll
    for (int i = 0; i < 4; ++i)
#pragma unroll
      for (int j = 0; j < 4; ++j)
        acc[i][j] =
            __builtin_amdgcn_mfma_f32_16x16x32_bf16(af[i], bf[j], acc[i][j], 0, 0, 0);
  }
#pragma unroll
  for (int j = 0; j < 4; ++j) {
    int col = n0 + wn * 64 + j * 16 + m15;
    float bv = (col < 1024) ? b0[col] : b1[col - 1024];
    float sc = (col < 1024) ? 0.125f : 1.0f;
#pragma unroll
    for (int i = 0; i < 4; ++i) {
      int rowb = m0 + wm * 64 + i * 16 + q4 * 4;
#pragma unroll
      for (int r = 0; r < 4; ++r)
        Cout[(rowb + r) * N + col] = f2b((acc[i][j][r] + bv) * sc);
    }
  }
}

// -------------------------------------- 64x128-tile GEMM (for small M) ------
template <int EPI>
__global__ __launch_bounds__(256) void gemm64_kernel(
    const ushort* __restrict__ A, const ushort* __restrict__ BT0,
    const ushort* __restrict__ BT1, int rowSplit, const float* __restrict__ b0,
    const float* __restrict__ b1, void* __restrict__ Cout, int M, int N, int K) {
  __shared__ ushort As[64 * 32];
  __shared__ ushort Bs[128 * 32];
  const int m0 = blockIdx.x * 64, n0 = blockIdx.y * 128;
  const ushort* BT = (m0 < rowSplit) ? BT0 : BT1;
  const float* bias = (m0 < rowSplit) ? b0 : b1;
  const int tid = threadIdx.x;
  const int w = tid >> 6, lane = tid & 63, m15 = lane & 15, q4 = lane >> 4;
  float4v acc[4][2] = {};
  const int ra = tid >> 2, ua = (tid & 3) * 8;
  const int c0 = tid, c1 = tid + 256;
  const int rb0 = c0 >> 2, ub0 = (c0 & 3) * 8;
  const int rb1 = c1 >> 2, ub1 = (c1 & 3) * 8;

  for (int kk = 0; kk < K; kk += 32) {
    __syncthreads();
    gld16(&A[(m0 + ra) * K + kk + ua], &As[tid * 8]);
    gld16(&BT[(n0 + rb0) * K + kk + ub0], &Bs[c0 * 8]);
    gld16(&BT[(n0 + rb1) * K + kk + ub1], &Bs[c1 * 8]);
    __syncthreads();
    short8 bf[2];
#pragma unroll
    for (int j = 0; j < 2; ++j)
      bf[j] = *(const short8*)(&Bs[(w * 32 + j * 16 + m15) * 32 + q4 * 8]);
#pragma unroll
    for (int i = 0; i < 4; ++i) {
      short8 af = *(const short8*)(&As[(i * 16 + m15) * 32 + q4 * 8]);
#pragma unroll
      for (int j = 0; j < 2; ++j)
        acc[i][j] =
            __builtin_amdgcn_mfma_f32_16x16x32_bf16(af, bf[j], acc[i][j], 0, 0, 0);
    }
  }
#pragma unroll
  for (int j = 0; j < 2; ++j) {
    int col = n0 + w * 32 + j * 16 + m15;
    float bv = bias[col];
#pragma unroll
    for (int i = 0; i < 4; ++i) {
      int rowb = m0 + i * 16 + q4 * 4;
#pragma unroll
      for (int r = 0; r < 4; ++r) {
        float v = acc[i][j][r] + bv;
        if (EPI == 1)
          ((float*)Cout)[(rowb + r) * N + col] = v;
        else
          ((ushort*)Cout)[(rowb + r) * N + col] = f2b(v);
      }
    }
  }
}

// ------------- Bhat batched GEMM with SHIFTED scatter: Bsh[b,h,s',t] --------
// Bhat[s][u] = 0.125 q[s].Qrel[u]. Shift applied at write: t = u+s-1023;
// t>=0 -> row s; t<0 -> row s-1, t+=2048 (drop row -1). Destinations are
// provably unique; only column t = s'+1025 (u==2048, zero B-term) is never
// written -> attn predicates it to 0.
__global__ __launch_bounds__(256) void bhat_kernel(
    const ushort* __restrict__ q, const ushort* __restrict__ Qrb,
    ushort* __restrict__ Bsh) {
  __shared__ ushort As[2 * 128 * 32];
  __shared__ ushort Bs[2 * 128 * 32];
  const int bs0 = blockIdx.x * 128, u0 = blockIdx.y * 128, h = blockIdx.z;
  const int tid = threadIdx.x;
  const int w = tid >> 6, lane = tid & 63, m15 = lane & 15, q4 = lane >> 4;
  const int wm = w & 1, wn = w >> 1;

#pragma unroll
  for (int c = 0; c < 4; ++c) {
    int unit = c * 256 + tid;
    int row = (unit >> 2) & 127, kh = unit >> 9, cu = unit & 3;
    gld16(&q[(bs0 + row) * 1024 + (h << 6) + kh * 32 + cu * 8], &As[unit * 8]);
    gld16(&Qrb[(u0 + row) * 1024 + (h << 6) + kh * 32 + cu * 8], &Bs[unit * 8]);
  }
  __syncthreads();

  float4v acc[4][4] = {};
#pragma unroll
  for (int kh = 0; kh < 2; ++kh) {
    short8 af[4], bf[4];
#pragma unroll
    for (int i = 0; i < 4; ++i)
      af[i] = *(const short8*)(&As[kh * 4096 + (wm * 64 + i * 16 + m15) * 32 + q4 * 8]);
#pragma unroll
    for (int j = 0; j < 4; ++j)
      bf[j] = *(const short8*)(&Bs[kh * 4096 + (wn * 64 + j * 16 + m15) * 32 + q4 * 8]);
#pragma unroll
    for (int i = 0; i < 4; ++i)
#pragma unroll
      for (int j = 0; j < 4; ++j)
        acc[i][j] =
            __builtin_amdgcn_mfma_f32_16x16x32_bf16(af[i], bf[j], acc[i][j], 0, 0, 0);
  }
  const int b = bs0 >> 10;
  const size_t base = ((size_t)((b << 4) + h)) << 21;
  const int sb = (bs0 & 1023) + wm * 64 + q4 * 4;
#pragma unroll
  for (int j = 0; j < 4; ++j) {
    int u = u0 + wn * 64 + j * 16 + m15;
#pragma unroll
    for (int i = 0; i < 4; ++i) {
#pragma unroll
      for (int r = 0; r < 4; ++r) {
        int s = sb + i * 16 + r;
        int t = u + s - 1023;
        int row = s;
        if (t < 0) { row = s - 1; t += 2048; }
        if (row >= 0)
          Bsh[base + ((size_t)row << 11) + t] = f2b(acc[i][j][r] * 0.125f);
      }
    }
  }
}

// ---------------- fused attention: QK + shifted-B + exp + PV ----------------
// Wave-independent: wave = (st s-tile 16 rows, th T-half). Chunks of 32 t.
// No barriers in the loop. exp-stage mapping (s=m15, t=q4*8+j) == P A-frag
// layout -> P built in-register; A-term goes through wave-private LDS.
// B and mask read as one uint4/lane/chunk (coalesced 64B row segments).
__global__ __launch_bounds__(256) void attn_kernel(
    const ushort* __restrict__ qb, const ushort* __restrict__ kv,
    const ushort* __restrict__ vt, const ushort* __restrict__ Bsh,
    const ushort* __restrict__ maskb, ushort* __restrict__ attn) {
  __shared__ float Asc[4][16][36];   // per-wave A-term scratch (C->exp remap)
  __shared__ float comb[2][16][68];
  __shared__ float csum2[2][32];

  const int tid = threadIdx.x;
  const int w = tid >> 6, lane = tid & 63, m15 = lane & 15, q4 = lane >> 4;
  const int st = w & 1, th = w >> 1;
  const int s0w = blockIdx.x * 32 + st * 16;
  const int h = blockIdx.y, b = blockIdx.z;

  const ushort* qp = &qb[((b << 10) + s0w + m15) * 1024 + (h << 6) + q4 * 8];
  const short8 af0 = *(const short8*)qp;
  const short8 af1 = *(const short8*)(qp + 32);

  const ushort* kvb = &kv[((size_t)(b << 11) * 2048) + (h << 6)];
  const ushort* vtb = &vt[((size_t)((b << 10) + (h << 6))) * 2048];
  const size_t bsbase = ((size_t)((b << 4) + h)) << 21;
  float* asc = &Asc[w][0][0];

  const int s_r = s0w + m15;   // this lane's s row in the exp mapping
  const int tof = q4 * 8;      // lane's t offset within chunk

  float lsum = 0.f;
  float4v oacc[4] = {};

  for (int ci = 0; ci < 32; ++ci) {
    const int t0 = th * 1024 + ci * 32;
    // chunk loads (all vectorized)
    short8 Kr[2][2], Vr[4];
#pragma unroll
    for (int nt = 0; nt < 2; ++nt) {
      const ushort* kp = &kvb[(size_t)(t0 + nt * 16 + m15) * 2048 + q4 * 8];
      Kr[nt][0] = *(const short8*)kp;
      Kr[nt][1] = *(const short8*)(kp + 32);
    }
#pragma unroll
    for (int nd = 0; nd < 4; ++nd)
      Vr[nd] = *(const short8*)(&vtb[(size_t)(nd * 16 + m15) * 2048 + t0 + tof]);
    uint4 bmv = *(const uint4*)(&Bsh[bsbase + ((size_t)s_r << 11) + t0 + tof]);
    uint4 mkv = *(const uint4*)(&maskb[(s_r << 11) + t0 + tof]);

    // QK -> C-layout
    float4v aacc[2];
#pragma unroll
    for (int nt = 0; nt < 2; ++nt) {
      float4v a = {0.f, 0.f, 0.f, 0.f};
      a = __builtin_amdgcn_mfma_f32_16x16x32_bf16(af0, Kr[nt][0], a, 0, 0, 0);
      a = __builtin_amdgcn_mfma_f32_16x16x32_bf16(af1, Kr[nt][1], a, 0, 0, 0);
      aacc[nt] = a;
    }
    // C-layout (s=q4*4+i, t=nt*16+m15) -> scratch -> exp mapping (s=m15,t=tof+j)
#pragma unroll
    for (int nt = 0; nt < 2; ++nt)
#pragma unroll
      for (int i = 0; i < 4; ++i)
        asc[(q4 * 4 + i) * 36 + nt * 16 + m15] = aacc[nt][i];
    float4 a0 = *(const float4*)(&asc[m15 * 36 + tof]);
    float4 a1 = *(const float4*)(&asc[m15 * 36 + tof + 4]);

    const int jz = s_r + 1025 - t0 - tof;   // zero-column j (u==2048)
    ushort pk[8];
    const ushort* bm = (const ushort*)&bmv;
    const ushort* mk = (const ushort*)&mkv;
#pragma unroll
    for (int j = 0; j < 8; ++j) {
      float bv = (j == jz) ? 0.f : b2f(bm[j]);
      float av = (j < 4) ? ((const float*)&a0)[j] : ((const float*)&a1)[j - 4];
      float p = __expf(av + bv + b2f(mk[j]));
      lsum += p;
      pk[j] = f2b(p);
    }
    short8 pfr = *(const short8*)pk;
#pragma unroll
    for (int nd = 0; nd < 4; ++nd)
      oacc[nd] = __builtin_amdgcn_mfma_f32_16x16x32_bf16(pfr, Vr[nd], oacc[nd], 0, 0, 0);
  }

  // lsum: lanes m15, m15+16, m15+32, m15+48 hold partial sums for row s_r
  lsum += __shfl_xor(lsum, 16, 64);
  lsum += __shfl_xor(lsum, 32, 64);
  if (q4 == 0) csum2[th][st * 16 + m15] = lsum;
  if (th == 1) {
#pragma unroll
    for (int nd = 0; nd < 4; ++nd)
#pragma unroll
      for (int i = 0; i < 4; ++i)
        comb[st][q4 * 4 + i][nd * 16 + m15] = oacc[nd][i];
  }
  __syncthreads();
  if (th == 0) {
#pragma unroll
    for (int i = 0; i < 4; ++i) {
      float ls = csum2[0][st * 16 + q4 * 4 + i] + csum2[1][st * 16 + q4 * 4 + i];
#pragma unroll
      for (int nd = 0; nd < 4; ++nd) {
        float v = oacc[nd][i] + comb[st][q4 * 4 + i][nd * 16 + m15];
        attn[((b << 10) + s0w + q4 * 4 + i) * 1024 + (h << 6) + nd * 16 + m15] =
            f2b(v / ls);
      }
    }
  }
}

// ---------------------------------------------------------------- launch ----
extern "C" void kernel_launch(void* const* d_in, const int* in_sizes, int n_in,
                              void* d_out, int out_size, void* d_ws,
                              size_t ws_size, hipStream_t stream) {
  const float* x = (const float*)d_in[0];
  const float* mem = (const float*)d_in[1];
  const float* mask = (const float*)d_in[2];
  const float* rel = (const float*)d_in[3];
  const float* Wq = (const float*)d_in[4];
  const float* bq = (const float*)d_in[5];
  const float* Wke = (const float*)d_in[6];
  const float* bke = (const float*)d_in[7];
  const float* Wkr = (const float*)d_in[8];
  const float* bkr = (const float*)d_in[9];
  const float* Wv = (const float*)d_in[10];
  const float* bv = (const float*)d_in[11];
  const float* Wo = (const float*)d_in[12];
  const float* bo = (const float*)d_in[13];
  float* out = (float*)d_out;

  ushort* ws = (ushort*)d_ws;
  ushort* xt = ws;                          // 4096x1024 (reused as vt)
  ushort* xbrel = xt + 4096 * 1024;         // [xb(2048); relb(2048)] x 1024
  ushort* WqT = xbrel + 4096 * 1024;
  ushort* WkeT = WqT + 1024 * 1024;
  ushort* WvT = WkeT + 1024 * 1024;
  ushort* WkrT = WvT + 1024 * 1024;
  ushort* WoT = WkrT + 1024 * 1024;
  ushort* kv = WoT + 1024 * 1024;           // 4096x2048 (K scaled, V)
  ushort* qr = kv + 4096 * 2048;            // [qbuf(2048); Qrb(2048)] x 1024
  ushort* attn = qr + 4096 * 1024;          // 2048x1024
  ushort* maskb = attn + 2048 * 1024;       // 1024x2048 bf16 * -1e9
  ushort* Bsh = maskb + 1024 * 2048;        // [b*16+h][1024 s][2048 t] shifted B
  ushort* relb = xbrel + 2048 * 1024;
  ushort* Qrb = qr + 2048 * 1024;
  ushort* vt = xt;

  concat_cvt_kernel<<<2048, 256, 0, stream>>>(x, mem, xt, xbrel);
  cvt2_kernel<<<2048, 256, 0, stream>>>(rel, mask, relb, maskb);
  transpose_cvt5_kernel<<<dim3(32, 32, 5), 256, 0, stream>>>(
      Wq, Wke, Wkr, Wv, Wo, WqT, WkeT, WkrT, WvT, WoT);

  gemm128_kernel<<<dim3(32, 16), 256, 0, stream>>>(xt, WkeT, bke, bv, kv,
                                                   4096, 2048, 1024);
  gemm64_kernel<0><<<dim3(64, 8), 256, 0, stream>>>(
      xbrel, WqT, WkrT, 2048, bq, bkr, qr, 4096, 1024, 1024);
  vtrans_kernel<<<dim3(128, 16), 256, 0, stream>>>(kv, vt);

  bhat_kernel<<<dim3(16, 16, 16), 256, 0, stream>>>(qr, Qrb, Bsh);

  attn_kernel<<<dim3(SEQ / 32, NH, BATCH), 256, 0, stream>>>(
      qr, kv, vt, Bsh, maskb, attn);

  gemm64_kernel<1><<<dim3(32, 8), 256, 0, stream>>>(
      attn, WoT, WoT, 1 << 30, bo, bo, out, 2048, 1024, 1024);
}